// Round 1
// baseline (408.850 us; speedup 1.0000x reference)
//
#include <hip/hip_runtime.h>
#include <hip/hip_bf16.h>

// DDLG autoencoder: 4 layers of out[b][o] = sum_f prob[o][f] * op_f(x[b][idx[o][0..7]])
// ops: {min, max, einstein-product-reduce, einstein-sum-reduce}; prob = softmax(w) (is_train=1)
// Layout strategy: activations kept TRANSPOSED (S, B) so column gathers become
// contiguous-row reads (coalesced over batch lanes).

#define BATCH 4096
#define LOG2B 12

// ---------------- 4096x4096 f32 transpose, 64x64 LDS tile ----------------
__global__ __launch_bounds__(256) void transpose4096(const float* __restrict__ in,
                                                     float* __restrict__ out) {
    __shared__ float tile[64][65];  // +1 pad: conflict-free transposed reads
    const int tx = threadIdx.x;     // 0..63
    const int ty = threadIdx.y;     // 0..3
    const int x0 = blockIdx.x * 64;
    const int y0 = blockIdx.y * 64;
#pragma unroll
    for (int r = 0; r < 16; ++r) {
        int row = ty + r * 4;
        tile[row][tx] = in[(size_t)(y0 + row) * 4096 + (x0 + tx)];
    }
    __syncthreads();
#pragma unroll
    for (int r = 0; r < 16; ++r) {
        int row = ty + r * 4;
        out[(size_t)(x0 + row) * 4096 + (y0 + tx)] = tile[tx][row];
    }
}

// ---------------- one DDLG layer ----------------
// xT: (S_in, BATCH)  outT: (S_out, BATCH)  w: (S_out,4)  idx: (S_out,8)
// grid = (BATCH/256, S_out), block = 256
__global__ __launch_bounds__(256) void ddlg_layer_k(const float* __restrict__ xT,
                                                    const float* __restrict__ w,
                                                    const int* __restrict__ idx,
                                                    const int* __restrict__ is_train,
                                                    float* __restrict__ outT) {
    const int o = blockIdx.y;
    const int b = (blockIdx.x << 8) + threadIdx.x;

    // --- per-output gate probabilities (wave-uniform) ---
    float p[4];
    {
        float wv[4];
#pragma unroll
        for (int c = 0; c < 4; ++c) wv[c] = w[(o << 2) + c];
        if (*is_train) {
            float m = fmaxf(fmaxf(wv[0], wv[1]), fmaxf(wv[2], wv[3]));
            float s = 0.0f;
#pragma unroll
            for (int c = 0; c < 4; ++c) { p[c] = __expf(wv[c] - m); s += p[c]; }
            float inv = 1.0f / s;
#pragma unroll
            for (int c = 0; c < 4; ++c) p[c] *= inv;
        } else {
            // one-hot(argmax), first-max semantics like jnp.argmax
            int a = 0; float best = wv[0];
#pragma unroll
            for (int c = 1; c < 4; ++c) if (wv[c] > best) { best = wv[c]; a = c; }
#pragma unroll
            for (int c = 0; c < 4; ++c) p[c] = (c == a) ? 1.0f : 0.0f;
        }
    }

    // --- gather 8 features: contiguous rows of xT, coalesced over b ---
    float f[8];
#pragma unroll
    for (int c = 0; c < 8; ++c) {
        int j = idx[(o << 3) + c];
        f[c] = xT[((size_t)j << LOG2B) + b];
    }

    // --- 4 reductions over the 8 connections ---
    float mn = f[0], mx = f[0], ein = f[0], coe = f[0];
#pragma unroll
    for (int c = 1; c < 8; ++c) {
        float v = f[c];
        mn = fminf(mn, v);
        mx = fmaxf(mx, v);
        float ab = ein * v;
        ein = ab / (2.0f - (ein + v - ab));       // Einstein product t-norm
        coe = (coe + v) / (1.0f + coe * v);       // Einstein sum t-conorm
    }

    outT[((size_t)o << LOG2B) + b] = p[0] * mn + p[1] * mx + p[2] * ein + p[3] * coe;
}

extern "C" void kernel_launch(void* const* d_in, const int* in_sizes, int n_in,
                              void* d_out, int out_size, void* d_ws, size_t ws_size,
                              hipStream_t stream) {
    const float* x        = (const float*)d_in[0];
    const float* w0       = (const float*)d_in[1];
    const float* w1       = (const float*)d_in[2];
    const float* w2       = (const float*)d_in[3];
    const float* w3       = (const float*)d_in[4];
    const int*   idx0     = (const int*)d_in[5];
    const int*   idx1     = (const int*)d_in[6];
    const int*   idx2     = (const int*)d_in[7];
    const int*   idx3     = (const int*)d_in[8];
    const int*   is_train = (const int*)d_in[9];
    float*       out      = (float*)d_out;

    // Workspace plan (peak 96 MB), each region reused only after its reader is done:
    //  xT  @ 32MB (64MB) ; h0T @ 0 (32MB) ; h1T @ 32MB (16MB) ;
    //  h2T @ 0 (32MB)    ; h3T @ 32MB (64MB)
    char* ws = (char*)d_ws;
    const size_t M32 = (size_t)32 << 20;
    float* xT  = (float*)(ws + M32);
    float* h0T = (float*)(ws);
    float* h1T = (float*)(ws + M32);
    float* h2T = (float*)(ws);
    float* h3T = (float*)(ws + M32);

    dim3 tblock(64, 4);
    dim3 tgrid(64, 64);
    transpose4096<<<tgrid, tblock, 0, stream>>>(x, xT);

    ddlg_layer_k<<<dim3(16, 2048), 256, 0, stream>>>(xT,  w0, idx0, is_train, h0T);
    ddlg_layer_k<<<dim3(16, 1024), 256, 0, stream>>>(h0T, w1, idx1, is_train, h1T);
    ddlg_layer_k<<<dim3(16, 2048), 256, 0, stream>>>(h1T, w2, idx2, is_train, h2T);
    ddlg_layer_k<<<dim3(16, 4096), 256, 0, stream>>>(h2T, w3, idx3, is_train, h3T);

    transpose4096<<<tgrid, tblock, 0, stream>>>(h3T, out);
}

// Round 2
// 294.352 us; speedup vs baseline: 1.3890x; 1.3890x over previous
//
#include <hip/hip_runtime.h>
#include <hip/hip_bf16.h>

// DDLG autoencoder: 4 layers of out[b][o] = sum_f prob[o][f] * op_f(x[b][idx[o][0..7]])
// ops: {min, max, einstein-product-reduce, einstein-sum-reduce}; prob = softmax(w).
//
// R1: divide elimination via t-norm isomorphisms.
//   ein-product: h(a)=(2-a)/a is a homomorphism onto (*, R+):
//        reduce = 2D/(N+D),  D=prod(f_i), N=prod(2-f_i)
//   ein-sum (tanh addition): g(a)=(1+a)/(1-a) homomorphism:
//        reduce = (N-D)/(N+D), N=prod(1+f_i), D=prod(1-f_i)
//   Both denominators >= 1 for f in [0,1]  ->  __fdividef safe.
// Layer 3 writes d_out in (B,S) directly via a 64x65 LDS transpose tile.

#define BATCH 4096
#define LOG2B 12

// ---------------- 4096x4096 f32 transpose, 64x64 LDS tile ----------------
__global__ __launch_bounds__(256) void transpose4096(const float* __restrict__ in,
                                                     float* __restrict__ out) {
    __shared__ float tile[64][65];
    const int tx = threadIdx.x;     // 0..63
    const int ty = threadIdx.y;     // 0..3
    const int x0 = blockIdx.x * 64;
    const int y0 = blockIdx.y * 64;
#pragma unroll
    for (int r = 0; r < 16; ++r) {
        int row = ty + r * 4;
        tile[row][tx] = in[(size_t)(y0 + row) * 4096 + (x0 + tx)];
    }
    __syncthreads();
#pragma unroll
    for (int r = 0; r < 16; ++r) {
        int row = ty + r * 4;
        out[(size_t)(x0 + row) * 4096 + (y0 + tx)] = tile[tx][row];
    }
}

// ---------------- per-output gate probabilities ----------------
__device__ __forceinline__ void gate_probs(const float* __restrict__ w, int o,
                                           int train, float p[4]) {
    float wv[4];
#pragma unroll
    for (int c = 0; c < 4; ++c) wv[c] = w[(o << 2) + c];
    if (train) {
        float m = fmaxf(fmaxf(wv[0], wv[1]), fmaxf(wv[2], wv[3]));
        float s = 0.0f;
#pragma unroll
        for (int c = 0; c < 4; ++c) { p[c] = __expf(wv[c] - m); s += p[c]; }
        float inv = __fdividef(1.0f, s);
#pragma unroll
        for (int c = 0; c < 4; ++c) p[c] *= inv;
    } else {
        int a = 0; float best = wv[0];
#pragma unroll
        for (int c = 1; c < 4; ++c) if (wv[c] > best) { best = wv[c]; a = c; }
#pragma unroll
        for (int c = 0; c < 4; ++c) p[c] = (c == a) ? 1.0f : 0.0f;
    }
}

// ---------------- the 4-op gate, divide-free reductions ----------------
__device__ __forceinline__ float ddlg_gate(const float f[8], const float p[4]) {
    float mn = f[0], mx = f[0];
    float De = f[0], Ne = 2.0f - f[0];   // ein-product: 2D/(N+D)
    float Nc = 1.0f + f[0], Dc = 1.0f - f[0];  // ein-sum: (N-D)/(N+D)
#pragma unroll
    for (int c = 1; c < 8; ++c) {
        float v = f[c];
        mn = fminf(mn, v);
        mx = fmaxf(mx, v);
        De *= v;
        Ne *= (2.0f - v);
        Nc *= (1.0f + v);
        Dc *= (1.0f - v);
    }
    float ein = __fdividef(2.0f * De, Ne + De);
    float coe = __fdividef(Nc - Dc, Nc + Dc);
    return p[0] * mn + p[1] * mx + p[2] * ein + p[3] * coe;
}

// ---------------- generic layer: (S_in,B) -> (S_out,B) ----------------
// grid = (BATCH/256, S_out), block = 256
__global__ __launch_bounds__(256) void ddlg_layer_k(const float* __restrict__ xT,
                                                    const float* __restrict__ w,
                                                    const int* __restrict__ idx,
                                                    const int* __restrict__ is_train,
                                                    float* __restrict__ outT) {
    const int o = blockIdx.y;
    const int b = (blockIdx.x << 8) + threadIdx.x;

    float p[4];
    gate_probs(w, o, *is_train, p);

    float f[8];
#pragma unroll
    for (int c = 0; c < 8; ++c) {
        int j = idx[(o << 3) + c];
        f[c] = xT[((size_t)j << LOG2B) + b];
    }

    outT[((size_t)o << LOG2B) + b] = ddlg_gate(f, p);
}

// ---------------- final layer: (S_in,B) -> (B,S_out) fused transpose ----
// grid = (BATCH/64, S_out/64), block = 256
__global__ __launch_bounds__(256) void ddlg_layer_tw(const float* __restrict__ xT,
                                                     const float* __restrict__ w,
                                                     const int* __restrict__ idx,
                                                     const int* __restrict__ is_train,
                                                     float* __restrict__ out,
                                                     int s_out) {
    __shared__ float tile[64][65];
    const int tx = threadIdx.x & 63;   // b-lane during compute, o-lane on store
    const int ty = threadIdx.x >> 6;   // wave id
    const int b0 = blockIdx.x << 6;
    const int o0 = blockIdx.y << 6;
    const int b = b0 + tx;
    const int train = *is_train;

#pragma unroll
    for (int i = 0; i < 16; ++i) {
        const int ol = (ty << 4) + i;      // wave-uniform output index
        const int o = o0 + ol;
        float p[4];
        gate_probs(w, o, train, p);
        float f[8];
#pragma unroll
        for (int c = 0; c < 8; ++c) {
            int j = idx[(o << 3) + c];
            f[c] = xT[((size_t)j << LOG2B) + b];
        }
        tile[ol][tx] = ddlg_gate(f, p);
    }
    __syncthreads();
#pragma unroll
    for (int i = 0; i < 16; ++i) {
        const int row = (ty << 4) + i;     // b_local
        out[(size_t)(b0 + row) * s_out + (o0 + tx)] = tile[tx][row];
    }
}

extern "C" void kernel_launch(void* const* d_in, const int* in_sizes, int n_in,
                              void* d_out, int out_size, void* d_ws, size_t ws_size,
                              hipStream_t stream) {
    const float* x        = (const float*)d_in[0];
    const float* w0       = (const float*)d_in[1];
    const float* w1       = (const float*)d_in[2];
    const float* w2       = (const float*)d_in[3];
    const float* w3       = (const float*)d_in[4];
    const int*   idx0     = (const int*)d_in[5];
    const int*   idx1     = (const int*)d_in[6];
    const int*   idx2     = (const int*)d_in[7];
    const int*   idx3     = (const int*)d_in[8];
    const int*   is_train = (const int*)d_in[9];
    float*       out      = (float*)d_out;

    // ws plan (peak 96 MB): xT @32MB (64MB); h0T @0 (32MB); h1T @32MB (16MB);
    // h2T @0 (32MB). Each region reused only after its reader finished.
    char* ws = (char*)d_ws;
    const size_t M32 = (size_t)32 << 20;
    float* xT  = (float*)(ws + M32);
    float* h0T = (float*)(ws);
    float* h1T = (float*)(ws + M32);
    float* h2T = (float*)(ws);

    transpose4096<<<dim3(64, 64), dim3(64, 4), 0, stream>>>(x, xT);

    ddlg_layer_k<<<dim3(16, 2048), 256, 0, stream>>>(xT,  w0, idx0, is_train, h0T);
    ddlg_layer_k<<<dim3(16, 1024), 256, 0, stream>>>(h0T, w1, idx1, is_train, h1T);
    ddlg_layer_k<<<dim3(16, 2048), 256, 0, stream>>>(h1T, w2, idx2, is_train, h2T);

    // final layer writes (B, S_out) directly
    ddlg_layer_tw<<<dim3(64, 64), 256, 0, stream>>>(h2T, w3, idx3, is_train, out, 4096);
}

// Round 3
// 246.636 us; speedup vs baseline: 1.6577x; 1.1935x over previous
//
#include <hip/hip_runtime.h>
#include <hip/hip_bf16.h>

// DDLG autoencoder: 4 layers of out[b][o] = sum_f prob[o][f] * op_f(x[b][idx[o][0..7]])
// R1: divide-free Einstein reductions via homomorphisms:
//     ein-product = 2D/(N+D),  D=prod(f), N=prod(2-f)
//     ein-sum     = (N-D)/(N+D), N=prod(1+f), D=prod(1-f)   (tanh addition)
// R2: 4 batch elems/thread (float4 gathers; amortize softmax+addr calc 4x),
//     raw v_rcp_f32 for all divides (denoms >= 1 for f in [0,1]),
//     float2 ext-vectors in the product chains for v_pk_* packed-FP32.

#define BATCH 4096
#define LOG2B 12

typedef float f2 __attribute__((ext_vector_type(2)));

__device__ __forceinline__ float fastrcp(float x) { return __builtin_amdgcn_rcpf(x); }

// ---------------- 4096x4096 f32 transpose, 64x64 LDS tile ----------------
__global__ __launch_bounds__(256) void transpose4096(const float* __restrict__ in,
                                                     float* __restrict__ out) {
    __shared__ float tile[64][65];
    const int tx = threadIdx.x;     // 0..63
    const int ty = threadIdx.y;     // 0..3
    const int x0 = blockIdx.x * 64;
    const int y0 = blockIdx.y * 64;
#pragma unroll
    for (int r = 0; r < 16; ++r) {
        int row = ty + r * 4;
        tile[row][tx] = in[(size_t)(y0 + row) * 4096 + (x0 + tx)];
    }
    __syncthreads();
#pragma unroll
    for (int r = 0; r < 16; ++r) {
        int row = ty + r * 4;
        out[(size_t)(x0 + row) * 4096 + (y0 + tx)] = tile[tx][row];
    }
}

// ---------------- per-output gate probabilities ----------------
__device__ __forceinline__ void gate_probs(const float* __restrict__ w, int o,
                                           int train, float p[4]) {
    float wv[4];
#pragma unroll
    for (int c = 0; c < 4; ++c) wv[c] = w[(o << 2) + c];
    if (train) {
        float m = fmaxf(fmaxf(wv[0], wv[1]), fmaxf(wv[2], wv[3]));
        float s = 0.0f;
#pragma unroll
        for (int c = 0; c < 4; ++c) { p[c] = __expf(wv[c] - m); s += p[c]; }
        float inv = fastrcp(s);
#pragma unroll
        for (int c = 0; c < 4; ++c) p[c] *= inv;
    } else {
        int a = 0; float best = wv[0];
#pragma unroll
        for (int c = 1; c < 4; ++c) if (wv[c] > best) { best = wv[c]; a = c; }
#pragma unroll
        for (int c = 0; c < 4; ++c) p[c] = (c == a) ? 1.0f : 0.0f;
    }
}

// ---------------- gate on a pair of batch elements ----------------
__device__ __forceinline__ f2 gate_pair(const f2 v[8], const float p[4]) {
    f2 mn = v[0], mx = v[0];
    f2 De = v[0], Ne = 2.0f - v[0];
    f2 Nc = 1.0f + v[0], Dc = 1.0f - v[0];
#pragma unroll
    for (int c = 1; c < 8; ++c) {
        f2 x = v[c];
        mn.x = fminf(mn.x, x.x); mn.y = fminf(mn.y, x.y);
        mx.x = fmaxf(mx.x, x.x); mx.y = fmaxf(mx.y, x.y);
        De *= x;
        Ne *= (2.0f - x);
        Nc *= (1.0f + x);
        Dc *= (1.0f - x);
    }
    f2 ein, coe;
    ein.x = (2.0f * De.x) * fastrcp(Ne.x + De.x);
    ein.y = (2.0f * De.y) * fastrcp(Ne.y + De.y);
    coe.x = (Nc.x - Dc.x) * fastrcp(Nc.x + Dc.x);
    coe.y = (Nc.y - Dc.y) * fastrcp(Nc.y + Dc.y);
    f2 r = p[0] * mn;
    r += p[1] * mx;
    r += p[2] * ein;
    r += p[3] * coe;
    return r;
}

// ---------------- generic layer: (S_in,B) -> (S_out,B), 4 b/thread ------
// grid = (BATCH/1024, S_out), block = 256
__global__ __launch_bounds__(256) void ddlg_layer_k(const float* __restrict__ xT,
                                                    const float* __restrict__ w,
                                                    const int* __restrict__ idx,
                                                    const int* __restrict__ is_train,
                                                    float* __restrict__ outT) {
    const int o  = blockIdx.y;
    const int b4 = (blockIdx.x << 10) + (threadIdx.x << 2);

    float p[4];
    gate_probs(w, o, *is_train, p);

    f2 lo[8], hi[8];
#pragma unroll
    for (int c = 0; c < 8; ++c) {
        int j = idx[(o << 3) + c];
        float4 F = *(const float4*)(xT + ((size_t)j << LOG2B) + b4);
        lo[c] = f2{F.x, F.y};
        hi[c] = f2{F.z, F.w};
    }
    f2 rl = gate_pair(lo, p);
    f2 rh = gate_pair(hi, p);
    *(float4*)(outT + ((size_t)o << LOG2B) + b4) = float4{rl.x, rl.y, rh.x, rh.y};
}

// ---------------- final layer: (S_in,B) -> (B,S_out), fused transpose ---
// tile = 64 o x 64 b per block; grid = (BATCH/64, S_out/64), block = 256
__global__ __launch_bounds__(256) void ddlg_layer_tw(const float* __restrict__ xT,
                                                     const float* __restrict__ w,
                                                     const int* __restrict__ idx,
                                                     const int* __restrict__ is_train,
                                                     float* __restrict__ out,
                                                     int s_out) {
    __shared__ float tile[64][65];   // [o_local][b_local]
    const int t  = threadIdx.x;
    const int og = t >> 4;           // 0..15: o-group within pass
    const int bq = (t & 15) << 2;    // 0,4,...,60: b-quad
    const int b0 = blockIdx.x << 6;
    const int o0 = blockIdx.y << 6;
    const int train = *is_train;

#pragma unroll
    for (int i = 0; i < 4; ++i) {
        const int ol = (i << 4) + og;
        const int o  = o0 + ol;
        float p[4];
        gate_probs(w, o, train, p);
        f2 lo[8], hi[8];
#pragma unroll
        for (int c = 0; c < 8; ++c) {
            int j = idx[(o << 3) + c];
            float4 F = *(const float4*)(xT + ((size_t)j << LOG2B) + b0 + bq);
            lo[c] = f2{F.x, F.y};
            hi[c] = f2{F.z, F.w};
        }
        f2 rl = gate_pair(lo, p);
        f2 rh = gate_pair(hi, p);
        *(float4*)(&tile[ol][bq]) = float4{rl.x, rl.y, rh.x, rh.y};
    }
    __syncthreads();
    // transposed store: out[b][o], lanes sweep o (coalesced 256B rows)
    const int col = t & 63;          // o_local
    const int r0  = t >> 6;          // 0..3
#pragma unroll
    for (int j = 0; j < 16; ++j) {
        const int row = r0 + (j << 2);   // b_local
        out[(size_t)(b0 + row) * s_out + (o0 + col)] = tile[col][row];
    }
}

extern "C" void kernel_launch(void* const* d_in, const int* in_sizes, int n_in,
                              void* d_out, int out_size, void* d_ws, size_t ws_size,
                              hipStream_t stream) {
    const float* x        = (const float*)d_in[0];
    const float* w0       = (const float*)d_in[1];
    const float* w1       = (const float*)d_in[2];
    const float* w2       = (const float*)d_in[3];
    const float* w3       = (const float*)d_in[4];
    const int*   idx0     = (const int*)d_in[5];
    const int*   idx1     = (const int*)d_in[6];
    const int*   idx2     = (const int*)d_in[7];
    const int*   idx3     = (const int*)d_in[8];
    const int*   is_train = (const int*)d_in[9];
    float*       out      = (float*)d_out;

    // ws plan (peak 96 MB): xT @32MB (64MB); h0T @0 (32MB); h1T @32MB (16MB,
    // overwrites dead xT); h2T @0 (32MB, overwrites dead h0T).
    char* ws = (char*)d_ws;
    const size_t M32 = (size_t)32 << 20;
    float* xT  = (float*)(ws + M32);
    float* h0T = (float*)(ws);
    float* h1T = (float*)(ws + M32);
    float* h2T = (float*)(ws);

    transpose4096<<<dim3(64, 64), dim3(64, 4), 0, stream>>>(x, xT);

    ddlg_layer_k<<<dim3(4, 2048), 256, 0, stream>>>(xT,  w0, idx0, is_train, h0T);
    ddlg_layer_k<<<dim3(4, 1024), 256, 0, stream>>>(h0T, w1, idx1, is_train, h1T);
    ddlg_layer_k<<<dim3(4, 2048), 256, 0, stream>>>(h1T, w2, idx2, is_train, h2T);

    ddlg_layer_tw<<<dim3(64, 64), 256, 0, stream>>>(h2T, w3, idx3, is_train, out, 4096);
}

// Round 4
// 210.453 us; speedup vs baseline: 1.9427x; 1.1719x over previous
//
#include <hip/hip_runtime.h>
#include <hip/hip_bf16.h>

// DDLG autoencoder: 4 layers of out[b][o] = sum_f prob[o][f] * op_f(x[b][idx[o][0..7]])
// R1: divide-free Einstein reductions via homomorphisms:
//     ein-product = 2D/(N+D),  D=prod(f), N=prod(2-f)
//     ein-sum     = (N-D)/(N+D), N=prod(1+f), D=prod(1-f)
// R2: multiple batch elems/thread, v_rcp_f32, f2 packed-fp32 chains.
// R3: fp16 activation storage (halves gather traffic; tables become L2-resident),
//     softmax probs hoisted into a precomputed table (one tiny dispatch),
//     tw: 64o x 128b tile, stride-133 LDS (conflict-free transposed reads).

#define BATCH 4096
#define LOG2B 12

typedef float    f2 __attribute__((ext_vector_type(2)));
typedef _Float16 h4 __attribute__((ext_vector_type(4)));
typedef _Float16 h8 __attribute__((ext_vector_type(8)));

__device__ __forceinline__ float fastrcp(float x) { return __builtin_amdgcn_rcpf(x); }

// ---------------- softmax/one-hot prob table ----------------
// layout: [0,2048) L0 | [2048,3072) L1 | [3072,5120) L2 | [5120,9216) L3
__global__ __launch_bounds__(256) void probs_k(const float* __restrict__ w0,
                                               const float* __restrict__ w1,
                                               const float* __restrict__ w2,
                                               const float* __restrict__ w3,
                                               const int* __restrict__ is_train,
                                               float4* __restrict__ probs) {
    int g = blockIdx.x * 256 + threadIdx.x;
    if (g >= 9216) return;
    const float* w; int o;
    if (g < 2048)      { w = w0; o = g; }
    else if (g < 3072) { w = w1; o = g - 2048; }
    else if (g < 5120) { w = w2; o = g - 3072; }
    else               { w = w3; o = g - 5120; }
    float wv[4];
#pragma unroll
    for (int c = 0; c < 4; ++c) wv[c] = w[(o << 2) + c];
    float p[4];
    if (*is_train) {
        float m = fmaxf(fmaxf(wv[0], wv[1]), fmaxf(wv[2], wv[3]));
        float s = 0.0f;
#pragma unroll
        for (int c = 0; c < 4; ++c) { p[c] = __expf(wv[c] - m); s += p[c]; }
        float inv = fastrcp(s);
#pragma unroll
        for (int c = 0; c < 4; ++c) p[c] *= inv;
    } else {
        int a = 0; float best = wv[0];
#pragma unroll
        for (int c = 1; c < 4; ++c) if (wv[c] > best) { best = wv[c]; a = c; }
#pragma unroll
        for (int c = 0; c < 4; ++c) p[c] = (c == a) ? 1.0f : 0.0f;
    }
    probs[g] = float4{p[0], p[1], p[2], p[3]};
}

// ---------------- 4096x4096: f32 (b,j) -> fp16 (j,b) transpose ----------
__global__ __launch_bounds__(256) void transpose_h(const float* __restrict__ in,
                                                   _Float16* __restrict__ out) {
    __shared__ float tile[64][65];
    const int tx = threadIdx.x;     // 0..63
    const int ty = threadIdx.y;     // 0..3
    const int x0 = blockIdx.x * 64; // j-range
    const int y0 = blockIdx.y * 64; // b-range
#pragma unroll
    for (int r = 0; r < 16; ++r) {
        int row = ty + r * 4;
        tile[row][tx] = in[(size_t)(y0 + row) * 4096 + (x0 + tx)];
    }
    __syncthreads();
#pragma unroll
    for (int r = 0; r < 16; ++r) {
        int row = ty + r * 4;
        out[(size_t)(x0 + row) * 4096 + (y0 + tx)] = (_Float16)tile[tx][row];
    }
}

// ---------------- divide-free gate on a packed pair ----------------
__device__ __forceinline__ f2 gate_pair(const f2 v[8], const float4 P) {
    f2 mn = v[0], mx = v[0];
    f2 De = v[0], Ne = 2.0f - v[0];
    f2 Nc = 1.0f + v[0], Dc = 1.0f - v[0];
#pragma unroll
    for (int c = 1; c < 8; ++c) {
        f2 x = v[c];
        mn.x = fminf(mn.x, x.x); mn.y = fminf(mn.y, x.y);
        mx.x = fmaxf(mx.x, x.x); mx.y = fmaxf(mx.y, x.y);
        De *= x;
        Ne *= (2.0f - x);
        Nc *= (1.0f + x);
        Dc *= (1.0f - x);
    }
    f2 ein, coe;
    ein.x = (2.0f * De.x) * fastrcp(Ne.x + De.x);
    ein.y = (2.0f * De.y) * fastrcp(Ne.y + De.y);
    coe.x = (Nc.x - Dc.x) * fastrcp(Nc.x + Dc.x);
    coe.y = (Nc.y - Dc.y) * fastrcp(Nc.y + Dc.y);
    f2 r = P.x * mn;
    r += P.y * mx;
    r += P.z * ein;
    r += P.w * coe;
    return r;
}

// ---------------- mid layer: fp16 (S_in,B) -> fp16 (S_out,B), 8 b/thread
// grid = (BATCH/2048, S_out), block = 256
__global__ __launch_bounds__(256) void ddlg_layer_h(const _Float16* __restrict__ xT,
                                                    const float4* __restrict__ probs,
                                                    const int* __restrict__ idx,
                                                    _Float16* __restrict__ outT) {
    const int o  = blockIdx.y;
    const int b8 = (blockIdx.x << 11) + (threadIdx.x << 3);

    const float4 P = probs[o];

    h8 raw[8];
#pragma unroll
    for (int c = 0; c < 8; ++c) {
        int j = idx[(o << 3) + c];
        raw[c] = *(const h8*)(xT + ((size_t)j << LOG2B) + b8);
    }

    h8 res;
#pragma unroll
    for (int q = 0; q < 4; ++q) {
        f2 v[8];
#pragma unroll
        for (int c = 0; c < 8; ++c)
            v[c] = f2{(float)raw[c][2 * q], (float)raw[c][2 * q + 1]};
        f2 r = gate_pair(v, P);
        res[2 * q]     = (_Float16)r.x;
        res[2 * q + 1] = (_Float16)r.y;
    }
    *(h8*)(outT + ((size_t)o << LOG2B) + b8) = res;
}

// ---------------- final layer: fp16 (S_in,B) -> f32 (B,S_out) -----------
// tile 64 o x 128 b; grid = (BATCH/128, S_out/64), block = 256
__global__ __launch_bounds__(256) void ddlg_layer_twh(const _Float16* __restrict__ xT,
                                                      const float4* __restrict__ probs,
                                                      const int* __restrict__ idx,
                                                      float* __restrict__ out) {
    __shared__ float tile[64][133];   // [o_local][b_local]; 133: conflict-free both phases
    const int t  = threadIdx.x;
    const int b0 = blockIdx.x << 7;   // 128 b per block
    const int o0 = blockIdx.y << 6;   // 64 o per block

#pragma unroll
    for (int p = 0; p < 8; ++p) {
        const int ol = (p << 3) + (t >> 5);   // wave-uniform per 32-lane group
        const int o  = o0 + ol;
        const int bl = (t & 31) << 2;         // 4 b per thread
        const float4 P = probs[5120 + o];
        f2 lo[8], hi[8];
#pragma unroll
        for (int c = 0; c < 8; ++c) {
            int j = idx[(o << 3) + c];
            h4 F = *(const h4*)(xT + ((size_t)j << LOG2B) + b0 + bl);
            lo[c] = f2{(float)F[0], (float)F[1]};
            hi[c] = f2{(float)F[2], (float)F[3]};
        }
        f2 rl = gate_pair(lo, P);
        f2 rh = gate_pair(hi, P);
        tile[ol][bl + 0] = rl.x;
        tile[ol][bl + 1] = rl.y;
        tile[ol][bl + 2] = rh.x;
        tile[ol][bl + 3] = rh.y;
    }
    __syncthreads();
    // transposed store: out[b][o], lanes sweep o (256B segments)
    const int col = t & 63;          // o_local
    const int r0  = t >> 6;          // 0..3
#pragma unroll
    for (int j = 0; j < 32; ++j) {
        const int row = r0 + (j << 2);   // b_local 0..127
        out[(size_t)(b0 + row) * 4096 + (o0 + col)] = tile[col][row];
    }
}

extern "C" void kernel_launch(void* const* d_in, const int* in_sizes, int n_in,
                              void* d_out, int out_size, void* d_ws, size_t ws_size,
                              hipStream_t stream) {
    const float* x        = (const float*)d_in[0];
    const float* w0       = (const float*)d_in[1];
    const float* w1       = (const float*)d_in[2];
    const float* w2       = (const float*)d_in[3];
    const float* w3       = (const float*)d_in[4];
    const int*   idx0     = (const int*)d_in[5];
    const int*   idx1     = (const int*)d_in[6];
    const int*   idx2     = (const int*)d_in[7];
    const int*   idx3     = (const int*)d_in[8];
    const int*   is_train = (const int*)d_in[9];
    float*       out      = (float*)d_out;

    // ws layout (fp16 activations): xT 32MB @0 | h0T 16MB @32M | h1T 8MB @48M |
    // h2T 16MB @56M | probs 147KB @72M.  Peak 72.2 MB.
    char* ws = (char*)d_ws;
    const size_t MB = (size_t)1 << 20;
    _Float16* xT    = (_Float16*)(ws);
    _Float16* h0T   = (_Float16*)(ws + 32 * MB);
    _Float16* h1T   = (_Float16*)(ws + 48 * MB);
    _Float16* h2T   = (_Float16*)(ws + 56 * MB);
    float4*   probs = (float4*)  (ws + 72 * MB);

    probs_k<<<36, 256, 0, stream>>>(w0, w1, w2, w3, is_train, probs);
    transpose_h<<<dim3(64, 64), dim3(64, 4), 0, stream>>>(x, xT);

    ddlg_layer_h<<<dim3(2, 2048), 256, 0, stream>>>(xT,  probs,        idx0, h0T);
    ddlg_layer_h<<<dim3(2, 1024), 256, 0, stream>>>(h0T, probs + 2048, idx1, h1T);
    ddlg_layer_h<<<dim3(2, 2048), 256, 0, stream>>>(h1T, probs + 3072, idx2, h2T);

    ddlg_layer_twh<<<dim3(32, 64), 256, 0, stream>>>(h2T, probs, idx3, out);
}

// Round 5
// 185.517 us; speedup vs baseline: 2.2038x; 1.1344x over previous
//
#include <hip/hip_runtime.h>
#include <hip/hip_bf16.h>

// DDLG autoencoder, fully fused: 4 layers of
//   out[b][o] = sum_f prob[o][f] * op_f(x[b][idx[o][0..7]])
// R1: divide-free Einstein reductions via homomorphisms:
//     ein-product = 2D/(N+D),  D=prod(f), N=prod(2-f)
//     ein-sum     = (N-D)/(N+D), N=prod(1+f), D=prod(1-f)
// R4: ONE kernel, whole network LDS-resident per batch-tile of 8.
//     LDS (fp16, [j][b] with b-stride 8 => 16B rows, ds_read_b128 gathers):
//       phase0: x @ [0,64K)      -> h0 @ [64K,96K)
//       phase1: h0               -> h1 @ [0,16K)    (x dead)
//       phase2: h1               -> h2 @ [64K,96K)  (h0 dead)
//       phase3: h2               -> global out      (direct, coalesced over o)
//     96 KB LDS, 1024 thr/block, 512 blocks (1 block/CU, 2 rounds).
//     Global traffic = read x (64MB) + write out (64MB) only.
//     min/max chains packed fp16 (exact); product chains f32 (underflow safety).

#define BATCH 4096

typedef float    f2 __attribute__((ext_vector_type(2)));
typedef _Float16 h8 __attribute__((ext_vector_type(8)));

__device__ __forceinline__ float fastrcp(float x) { return __builtin_amdgcn_rcpf(x); }

// ---------------- softmax/one-hot prob table ----------------
// layout: [0,2048) L0 | [2048,3072) L1 | [3072,5120) L2 | [5120,9216) L3
__global__ __launch_bounds__(256) void probs_k(const float* __restrict__ w0,
                                               const float* __restrict__ w1,
                                               const float* __restrict__ w2,
                                               const float* __restrict__ w3,
                                               const int* __restrict__ is_train,
                                               float4* __restrict__ probs) {
    int g = blockIdx.x * 256 + threadIdx.x;
    if (g >= 9216) return;
    const float* w; int o;
    if (g < 2048)      { w = w0; o = g; }
    else if (g < 3072) { w = w1; o = g - 2048; }
    else if (g < 5120) { w = w2; o = g - 3072; }
    else               { w = w3; o = g - 5120; }
    float wv[4];
#pragma unroll
    for (int c = 0; c < 4; ++c) wv[c] = w[(o << 2) + c];
    float p[4];
    if (*is_train) {
        float m = fmaxf(fmaxf(wv[0], wv[1]), fmaxf(wv[2], wv[3]));
        float s = 0.0f;
#pragma unroll
        for (int c = 0; c < 4; ++c) { p[c] = __expf(wv[c] - m); s += p[c]; }
        float inv = fastrcp(s);
#pragma unroll
        for (int c = 0; c < 4; ++c) p[c] *= inv;
    } else {
        int a = 0; float best = wv[0];
#pragma unroll
        for (int c = 1; c < 4; ++c) if (wv[c] > best) { best = wv[c]; a = c; }
#pragma unroll
        for (int c = 0; c < 4; ++c) p[c] = (c == a) ? 1.0f : 0.0f;
    }
    probs[g] = float4{p[0], p[1], p[2], p[3]};
}

// ---------------- Einstein chains on a packed pair (f32) ----------------
__device__ __forceinline__ void ein_pair(const f2 v[8], f2& ein, f2& coe) {
    f2 De = v[0], Ne = 2.0f - v[0];
    f2 Nc = 1.0f + v[0], Dc = 1.0f - v[0];
#pragma unroll
    for (int c = 1; c < 8; ++c) {
        f2 x = v[c];
        De *= x;
        Ne *= (2.0f - x);
        Nc *= (1.0f + x);
        Dc *= (1.0f - x);
    }
    ein.x = (2.0f * De.x) * fastrcp(Ne.x + De.x);
    ein.y = (2.0f * De.y) * fastrcp(Ne.y + De.y);
    coe.x = (Nc.x - Dc.x) * fastrcp(Nc.x + Dc.x);
    coe.y = (Nc.y - Dc.y) * fastrcp(Nc.y + Dc.y);
}

// ---------------- one output o, all 8 batch lanes ----------------
// src: LDS table (S_in rows x 8 fp16); writes 8 f32 results to r8[0..7]
__device__ __forceinline__ void gate8(const _Float16* __restrict__ src,
                                      const int4* __restrict__ idx,
                                      const float4* __restrict__ probs,
                                      int o, float r8[8]) {
    const int4 i0 = idx[o * 2];
    const int4 i1 = idx[o * 2 + 1];
    const float4 P = probs[o];
    h8 raw[8];
    raw[0] = *(const h8*)(src + (i0.x << 3));
    raw[1] = *(const h8*)(src + (i0.y << 3));
    raw[2] = *(const h8*)(src + (i0.z << 3));
    raw[3] = *(const h8*)(src + (i0.w << 3));
    raw[4] = *(const h8*)(src + (i1.x << 3));
    raw[5] = *(const h8*)(src + (i1.y << 3));
    raw[6] = *(const h8*)(src + (i1.z << 3));
    raw[7] = *(const h8*)(src + (i1.w << 3));

    // packed fp16 min/max (exact: inputs are fp16)
    h8 mnv = raw[0], mxv = raw[0];
#pragma unroll
    for (int c = 1; c < 8; ++c) {
        mnv = __builtin_elementwise_min(mnv, raw[c]);
        mxv = __builtin_elementwise_max(mxv, raw[c]);
    }

#pragma unroll
    for (int q = 0; q < 4; ++q) {
        f2 v[8];
#pragma unroll
        for (int c = 0; c < 8; ++c)
            v[c] = f2{(float)raw[c][2 * q], (float)raw[c][2 * q + 1]};
        f2 ein, coe;
        ein_pair(v, ein, coe);
        f2 r;
        r.x = P.x * (float)mnv[2 * q]     + P.y * (float)mxv[2 * q];
        r.y = P.x * (float)mnv[2 * q + 1] + P.y * (float)mxv[2 * q + 1];
        r += P.z * ein;
        r += P.w * coe;
        r8[2 * q]     = r.x;
        r8[2 * q + 1] = r.y;
    }
}

__device__ __forceinline__ void layer_pass(const _Float16* __restrict__ src,
                                           _Float16* __restrict__ dst,
                                           const int4* __restrict__ idx,
                                           const float4* __restrict__ probs,
                                           int o) {
    float r8[8];
    gate8(src, idx, probs, o, r8);
    h8 res;
#pragma unroll
    for (int i = 0; i < 8; ++i) res[i] = (_Float16)r8[i];
    *(h8*)(dst + (o << 3)) = res;
}

// ---------------- the fused network ----------------
// grid = 512 (one block per 8-batch tile), block = 1024
__global__ __launch_bounds__(1024) void ddlg_fused(const float* __restrict__ x,
                                                   const float4* __restrict__ probs,
                                                   const int4* __restrict__ idx0,
                                                   const int4* __restrict__ idx1,
                                                   const int4* __restrict__ idx2,
                                                   const int4* __restrict__ idx3,
                                                   float* __restrict__ out) {
    __shared__ __align__(16) _Float16 lds[49152];   // 96 KB
    const int t  = threadIdx.x;
    const int b0 = blockIdx.x << 3;

    const _Float16* xl = lds;           // 32768 elems = 64 KB
    _Float16*       h0 = lds + 32768;   // 16384 elems = 32 KB
    _Float16*       h1 = lds;           //  8192 elems = 16 KB (overlays dead x)
    _Float16*       h2 = lds + 32768;   // 16384 elems = 32 KB (overlays dead h0)

    // ---- stage x rows b0..b0+7 -> lds[j*8 + r] (f32 -> fp16) ----
    {
        const int r = t & 7;
        const int c = t >> 3;     // 0..127
        const float* xrow = x + (size_t)(b0 + r) * 4096;
#pragma unroll
        for (int k = 0; k < 8; ++k) {
            const int j0 = (c << 2) + (k << 9);
            const float4 F = *(const float4*)(xrow + j0);
            lds[((j0 + 0) << 3) + r] = (_Float16)F.x;
            lds[((j0 + 1) << 3) + r] = (_Float16)F.y;
            lds[((j0 + 2) << 3) + r] = (_Float16)F.z;
            lds[((j0 + 3) << 3) + r] = (_Float16)F.w;
        }
    }
    __syncthreads();

    // ---- L0: 4096 -> 2048 ----
    layer_pass(xl, h0, idx0, probs, t);
    layer_pass(xl, h0, idx0, probs, t + 1024);
    __syncthreads();

    // ---- L1: 2048 -> 1024 ----
    layer_pass(h0, h1, idx1, probs + 2048, t);
    __syncthreads();

    // ---- L2: 1024 -> 2048 ----
    layer_pass(h1, h2, idx2, probs + 3072, t);
    layer_pass(h1, h2, idx2, probs + 3072, t + 1024);
    __syncthreads();

    // ---- L3: 2048 -> 4096, direct global store (lanes sweep o: coalesced) ----
#pragma unroll
    for (int p = 0; p < 4; ++p) {
        const int o = (p << 10) + t;
        float r8[8];
        gate8(h2, idx3, probs + 5120, o, r8);
#pragma unroll
        for (int b = 0; b < 8; ++b)
            out[(size_t)(b0 + b) * 4096 + o] = r8[b];
    }
}

extern "C" void kernel_launch(void* const* d_in, const int* in_sizes, int n_in,
                              void* d_out, int out_size, void* d_ws, size_t ws_size,
                              hipStream_t stream) {
    const float* x        = (const float*)d_in[0];
    const float* w0       = (const float*)d_in[1];
    const float* w1       = (const float*)d_in[2];
    const float* w2       = (const float*)d_in[3];
    const float* w3       = (const float*)d_in[4];
    const int4*  idx0     = (const int4*)d_in[5];
    const int4*  idx1     = (const int4*)d_in[6];
    const int4*  idx2     = (const int4*)d_in[7];
    const int4*  idx3     = (const int4*)d_in[8];
    const int*   is_train = (const int*)d_in[9];
    float*       out      = (float*)d_out;

    float4* probs = (float4*)d_ws;   // 9216 * 16 B = 147 KB

    probs_k<<<36, 256, 0, stream>>>(w0, w1, w2, w3, is_train, probs);
    ddlg_fused<<<512, 1024, 0, stream>>>(x, probs, idx0, idx1, idx2, idx3, out);
}

// Round 6
// 173.134 us; speedup vs baseline: 2.3615x; 1.0715x over previous
//
#include <hip/hip_runtime.h>
#include <hip/hip_bf16.h>

// DDLG autoencoder, fully fused, batch-tile 4:
//   out[b][o] = sum_f prob[o][f] * op_f(x[b][idx[o][0..7]])
// R1: divide-free Einstein reductions via homomorphisms:
//     ein-product = 2D/(N+D),  D=prod(f), N=prod(2-f)
//     ein-sum     = (N-D)/(N+D), N=prod(1+f), D=prod(1-f)
// R5: 48 KB LDS (batch tile 4) -> 2 blocks/CU, 32 waves/CU (was 96 KB, 1 block).
//     LDS overlays (fp16, rows of 4 = 8 B, ds_read_b64 gathers):
//       x  @ elems [0,16384)      (32 KB)
//       h0 @ elems [16384,24576)  (16 KB)
//       h1 @ elems [0,4096)       ( 8 KB, over dead x)
//       h2 @ elems [16384,24576)  (16 KB, over dead h0)
//     Staging: thread t owns column j: 4 scalar coalesced global loads ->
//     one stride-1 ds_write_b64 (conflict-free; R4's scalar b16 scatter was
//     a same-bank 64-way pileup).
//     Chains in FMA form (Nc+=Nc*v, Dc-=Dc*v), single rcp finale:
//     r = rcp((Ne+De)(Nc+Dc)); products bounded by prod(2+f-f^2) <= 2.25^8.

#define BATCH 4096

typedef float    f2 __attribute__((ext_vector_type(2)));
typedef _Float16 h4 __attribute__((ext_vector_type(4)));

__device__ __forceinline__ float fastrcp(float x) { return __builtin_amdgcn_rcpf(x); }

// ---------------- softmax/one-hot prob table ----------------
// layout: [0,2048) L0 | [2048,3072) L1 | [3072,5120) L2 | [5120,9216) L3
__global__ __launch_bounds__(256) void probs_k(const float* __restrict__ w0,
                                               const float* __restrict__ w1,
                                               const float* __restrict__ w2,
                                               const float* __restrict__ w3,
                                               const int* __restrict__ is_train,
                                               float4* __restrict__ probs) {
    int g = blockIdx.x * 256 + threadIdx.x;
    if (g >= 9216) return;
    const float* w; int o;
    if (g < 2048)      { w = w0; o = g; }
    else if (g < 3072) { w = w1; o = g - 2048; }
    else if (g < 5120) { w = w2; o = g - 3072; }
    else               { w = w3; o = g - 5120; }
    float wv[4];
#pragma unroll
    for (int c = 0; c < 4; ++c) wv[c] = w[(o << 2) + c];
    float p[4];
    if (*is_train) {
        float m = fmaxf(fmaxf(wv[0], wv[1]), fmaxf(wv[2], wv[3]));
        float s = 0.0f;
#pragma unroll
        for (int c = 0; c < 4; ++c) { p[c] = __expf(wv[c] - m); s += p[c]; }
        float inv = fastrcp(s);
#pragma unroll
        for (int c = 0; c < 4; ++c) p[c] *= inv;
    } else {
        int a = 0; float best = wv[0];
#pragma unroll
        for (int c = 1; c < 4; ++c) if (wv[c] > best) { best = wv[c]; a = c; }
#pragma unroll
        for (int c = 0; c < 4; ++c) p[c] = (c == a) ? 1.0f : 0.0f;
    }
    probs[g] = float4{p[0], p[1], p[2], p[3]};
}

// ---------------- one output o, 4 batch lanes ----------------
__device__ __forceinline__ void gate4(const _Float16* __restrict__ src,
                                      const int4* __restrict__ idx,
                                      const float4* __restrict__ probs,
                                      int o, float r4[4]) {
    const int4 i0 = idx[o * 2];
    const int4 i1 = idx[o * 2 + 1];
    const float4 P = probs[o];
    h4 raw[8];
    raw[0] = *(const h4*)(src + (i0.x << 2));
    raw[1] = *(const h4*)(src + (i0.y << 2));
    raw[2] = *(const h4*)(src + (i0.z << 2));
    raw[3] = *(const h4*)(src + (i0.w << 2));
    raw[4] = *(const h4*)(src + (i1.x << 2));
    raw[5] = *(const h4*)(src + (i1.y << 2));
    raw[6] = *(const h4*)(src + (i1.z << 2));
    raw[7] = *(const h4*)(src + (i1.w << 2));

    // packed fp16 min/max (exact: inputs are fp16)
    h4 mnv = raw[0], mxv = raw[0];
#pragma unroll
    for (int c = 1; c < 8; ++c) {
        mnv = __builtin_elementwise_min(mnv, raw[c]);
        mxv = __builtin_elementwise_max(mxv, raw[c]);
    }

#pragma unroll
    for (int q = 0; q < 2; ++q) {
        f2 v0 = f2{(float)raw[0][2 * q], (float)raw[0][2 * q + 1]};
        f2 De = v0, Ne = 2.0f - v0;
        f2 Nc = 1.0f + v0, Dc = 1.0f - v0;
#pragma unroll
        for (int c = 1; c < 8; ++c) {
            f2 v = f2{(float)raw[c][2 * q], (float)raw[c][2 * q + 1]};
            De *= v;
            Ne *= (2.0f - v);
            Nc += Nc * v;   // fma: Nc *= (1+v)
            Dc -= Dc * v;   // fma: Dc *= (1-v)
        }
        f2 s1 = Ne + De, s2 = Nc + Dc, d1 = Nc - Dc;
        float r0 = fastrcp(s1.x * s2.x);
        float r1 = fastrcp(s1.y * s2.y);
        float einx = (2.0f * De.x * s2.x) * r0;
        float einy = (2.0f * De.y * s2.y) * r1;
        float coex = (d1.x * s1.x) * r0;
        float coey = (d1.y * s1.y) * r1;
        r4[2 * q]     = P.x * (float)mnv[2 * q]     + P.y * (float)mxv[2 * q]     + P.z * einx + P.w * coex;
        r4[2 * q + 1] = P.x * (float)mnv[2 * q + 1] + P.y * (float)mxv[2 * q + 1] + P.z * einy + P.w * coey;
    }
}

__device__ __forceinline__ void layer_pass(const _Float16* __restrict__ src,
                                           _Float16* __restrict__ dst,
                                           const int4* __restrict__ idx,
                                           const float4* __restrict__ probs,
                                           int o) {
    float r4[4];
    gate4(src, idx, probs, o, r4);
    h4 res;
#pragma unroll
    for (int i = 0; i < 4; ++i) res[i] = (_Float16)r4[i];
    *(h4*)(dst + (o << 2)) = res;
}

// ---------------- the fused network ----------------
// grid = 1024 (one block per 4-batch tile), block = 1024, 2 blocks/CU
__global__ __launch_bounds__(1024, 8) void ddlg_fused(const float* __restrict__ x,
                                                      const float4* __restrict__ probs,
                                                      const int4* __restrict__ idx0,
                                                      const int4* __restrict__ idx1,
                                                      const int4* __restrict__ idx2,
                                                      const int4* __restrict__ idx3,
                                                      float* __restrict__ out) {
    __shared__ __align__(16) _Float16 lds[24576];   // 48 KB
    const int t  = threadIdx.x;
    const int b0 = blockIdx.x << 2;

    const _Float16* xl = lds;           // 16384 elems = 32 KB
    _Float16*       h0 = lds + 16384;   //  8192 elems = 16 KB
    _Float16*       h1 = lds;           //  4096 elems =  8 KB (over dead x)
    _Float16*       h2 = lds + 16384;   //  8192 elems = 16 KB (over dead h0)

    // ---- stage x columns: thread owns j; 4 coalesced scalar loads -> b64 row ----
#pragma unroll
    for (int c = 0; c < 4; ++c) {
        const int j = (c << 10) + t;
        const float v0 = x[(size_t)(b0 + 0) * 4096 + j];
        const float v1 = x[(size_t)(b0 + 1) * 4096 + j];
        const float v2 = x[(size_t)(b0 + 2) * 4096 + j];
        const float v3 = x[(size_t)(b0 + 3) * 4096 + j];
        h4 hv;
        hv[0] = (_Float16)v0; hv[1] = (_Float16)v1;
        hv[2] = (_Float16)v2; hv[3] = (_Float16)v3;
        *(h4*)(lds + (j << 2)) = hv;    // stride-1 ds_write_b64: conflict-free
    }
    __syncthreads();

    // ---- L0: 4096 -> 2048 ----
    layer_pass(xl, h0, idx0, probs, t);
    layer_pass(xl, h0, idx0, probs, t + 1024);
    __syncthreads();

    // ---- L1: 2048 -> 1024 ----
    layer_pass(h0, h1, idx1, probs + 2048, t);
    __syncthreads();

    // ---- L2: 1024 -> 2048 ----
    layer_pass(h1, h2, idx2, probs + 3072, t);
    layer_pass(h1, h2, idx2, probs + 3072, t + 1024);
    __syncthreads();

    // ---- L3: 2048 -> 4096, direct global store (lanes sweep o: coalesced) ----
#pragma unroll
    for (int p = 0; p < 4; ++p) {
        const int o = (p << 10) + t;
        float r4[4];
        gate4(h2, idx3, probs + 5120, o, r4);
#pragma unroll
        for (int b = 0; b < 4; ++b)
            out[(size_t)(b0 + b) * 4096 + o] = r4[b];
    }
}

extern "C" void kernel_launch(void* const* d_in, const int* in_sizes, int n_in,
                              void* d_out, int out_size, void* d_ws, size_t ws_size,
                              hipStream_t stream) {
    const float* x        = (const float*)d_in[0];
    const float* w0       = (const float*)d_in[1];
    const float* w1       = (const float*)d_in[2];
    const float* w2       = (const float*)d_in[3];
    const float* w3       = (const float*)d_in[4];
    const int4*  idx0     = (const int4*)d_in[5];
    const int4*  idx1     = (const int4*)d_in[6];
    const int4*  idx2     = (const int4*)d_in[7];
    const int4*  idx3     = (const int4*)d_in[8];
    const int*   is_train = (const int*)d_in[9];
    float*       out      = (float*)d_out;

    float4* probs = (float4*)d_ws;   // 9216 * 16 B = 147 KB

    probs_k<<<36, 256, 0, stream>>>(w0, w1, w2, w3, is_train, probs);
    ddlg_fused<<<1024, 1024, 0, stream>>>(x, probs, idx0, idx1, idx2, idx3, out);
}

// Round 7
// 164.496 us; speedup vs baseline: 2.4855x; 1.0525x over previous
//
#include <hip/hip_runtime.h>
#include <hip/hip_bf16.h>

// DDLG autoencoder, fully fused, batch-tile 4, ALL-fp16 packed compute.
//   out[b][o] = sum_f prob[o][f] * op_f(x[b][idx[o][0..7]])
// R1: divide-free Einstein reductions via homomorphisms:
//     ein-product = 2D/(N+D),  D=prod(f), N=prod(2-f)
//     ein-sum     = (N-D)/(N+D), N=prod(1+f), D=prod(1-f)
// R5: 48 KB LDS, 1024-thr blocks, 2 blocks/CU; conflict-free staging.
// R6: chains/min/max/finale in packed fp16 (v_pk_*_f16, 2 elems/inst) --
//     removes the fp16->f32 cvt storm and halves chain inst count.
//     Two separate fp16 rcps (s1,s2 <= 257 << 65504; fused s1*s2 could
//     overflow fp16). idx pre-scaled to element offsets; probs pre-packed
//     to fp16 quads (prep_k, one tiny dispatch).
//     LDS overlays (fp16 rows of 4 = 8 B, ds_read_b64 gathers):
//       x @ [0,16384) | h0 @ [16384,24576) | h1 @ [0,4096) | h2 @ [16384,24576)

#define BATCH 4096

typedef _Float16 h4 __attribute__((ext_vector_type(4)));

__device__ __forceinline__ float fastrcp(float x) { return __builtin_amdgcn_rcpf(x); }
__device__ __forceinline__ _Float16 hrcp(_Float16 x) {
#if __has_builtin(__builtin_amdgcn_rcph)
    return __builtin_amdgcn_rcph(x);
#else
    return (_Float16)__builtin_amdgcn_rcpf((float)x);
#endif
}
__device__ __forceinline__ h4 splat(_Float16 s) { h4 v = {s, s, s, s}; return v; }

// ---------------- prep: fp16 prob table + pre-scaled idx ----------------
// probsH: [0,2048) L0 | [2048,3072) L1 | [3072,5120) L2 | [5120,9216) L3
// idxS (int4 units): L0 @0 (4096) | L1 @4096 (2048) | L2 @6144 (4096) | L3 @10240 (8192)
__global__ __launch_bounds__(256) void prep_k(const float* __restrict__ w0,
                                              const float* __restrict__ w1,
                                              const float* __restrict__ w2,
                                              const float* __restrict__ w3,
                                              const int* __restrict__ is_train,
                                              const int4* __restrict__ idx0,
                                              const int4* __restrict__ idx1,
                                              const int4* __restrict__ idx2,
                                              const int4* __restrict__ idx3,
                                              h4* __restrict__ probsH,
                                              int4* __restrict__ idxS) {
    const int blk = blockIdx.x;
    if (blk < 36) {
        int g = blk * 256 + threadIdx.x;
        if (g >= 9216) return;
        const float* w; int o;
        if (g < 2048)      { w = w0; o = g; }
        else if (g < 3072) { w = w1; o = g - 2048; }
        else if (g < 5120) { w = w2; o = g - 3072; }
        else               { w = w3; o = g - 5120; }
        float wv[4];
#pragma unroll
        for (int c = 0; c < 4; ++c) wv[c] = w[(o << 2) + c];
        float p[4];
        if (*is_train) {
            float m = fmaxf(fmaxf(wv[0], wv[1]), fmaxf(wv[2], wv[3]));
            float s = 0.0f;
#pragma unroll
            for (int c = 0; c < 4; ++c) { p[c] = __expf(wv[c] - m); s += p[c]; }
            float inv = fastrcp(s);
#pragma unroll
            for (int c = 0; c < 4; ++c) p[c] *= inv;
        } else {
            int a = 0; float best = wv[0];
#pragma unroll
            for (int c = 1; c < 4; ++c) if (wv[c] > best) { best = wv[c]; a = c; }
#pragma unroll
            for (int c = 0; c < 4; ++c) p[c] = (c == a) ? 1.0f : 0.0f;
        }
        probsH[g] = h4{(_Float16)p[0], (_Float16)p[1], (_Float16)p[2], (_Float16)p[3]};
    } else {
        int g = (blk - 36) * 256 + threadIdx.x;   // 0..18431 int4s
        const int4* src; int off;
        if (g < 4096)       { src = idx0; off = g; }
        else if (g < 6144)  { src = idx1; off = g - 4096; }
        else if (g < 10240) { src = idx2; off = g - 6144; }
        else                { src = idx3; off = g - 10240; }
        int4 v = src[off];
        idxS[g] = int4{v.x << 2, v.y << 2, v.z << 2, v.w << 2};
    }
}

// ---------------- one output o, 4 batch lanes, all fp16 ----------------
__device__ __forceinline__ h4 gate4h(const _Float16* __restrict__ src,
                                     const int4* __restrict__ idx,   // pre-scaled
                                     const h4* __restrict__ probs,
                                     int o) {
    const int4 i0 = idx[o * 2];
    const int4 i1 = idx[o * 2 + 1];
    const h4 P = probs[o];
    h4 raw[8];
    raw[0] = *(const h4*)(src + i0.x);
    raw[1] = *(const h4*)(src + i0.y);
    raw[2] = *(const h4*)(src + i0.z);
    raw[3] = *(const h4*)(src + i0.w);
    raw[4] = *(const h4*)(src + i1.x);
    raw[5] = *(const h4*)(src + i1.y);
    raw[6] = *(const h4*)(src + i1.z);
    raw[7] = *(const h4*)(src + i1.w);

    const h4 one = splat((_Float16)1.0f);
    const h4 two = splat((_Float16)2.0f);

    h4 mn = raw[0], mx = raw[0], De = raw[0];
    h4 Ne = two - raw[0];
    h4 Nc = one + raw[0];
    h4 Dc = one - raw[0];
#pragma unroll
    for (int c = 1; c < 8; ++c) {
        h4 v = raw[c];
        mn = __builtin_elementwise_min(mn, v);
        mx = __builtin_elementwise_max(mx, v);
        De *= v;
        Ne *= (two - v);
        Nc += Nc * v;   // pk_fma: Nc *= (1+v)
        Dc -= Dc * v;   // pk_fma: Dc *= (1-v)
    }
    h4 s1 = Ne + De;    // in [1, 257]: fp16-safe
    h4 s2 = Nc + Dc;    // in [1, 257]
    h4 d1 = Nc - Dc;
    h4 r1, r2;
#pragma unroll
    for (int e = 0; e < 4; ++e) { r1[e] = hrcp(s1[e]); r2[e] = hrcp(s2[e]); }
    h4 ein = (De + De) * r1;
    h4 coe = d1 * r2;
    h4 res = splat(P[0]) * mn;
    res += splat(P[1]) * mx;
    res += splat(P[2]) * ein;
    res += splat(P[3]) * coe;
    return res;
}

__device__ __forceinline__ void layer_pass(const _Float16* __restrict__ src,
                                           _Float16* __restrict__ dst,
                                           const int4* __restrict__ idx,
                                           const h4* __restrict__ probs,
                                           int o) {
    h4 r = gate4h(src, idx, probs, o);
    *(h4*)(dst + (o << 2)) = r;
}

// ---------------- the fused network ----------------
// grid = 1024 (one block per 4-batch tile), block = 1024, 2 blocks/CU
__global__ __launch_bounds__(1024, 8) void ddlg_fused(const float* __restrict__ x,
                                                      const h4* __restrict__ probsH,
                                                      const int4* __restrict__ idxS,
                                                      float* __restrict__ out) {
    __shared__ __align__(16) _Float16 lds[24576];   // 48 KB
    const int t  = threadIdx.x;
    const int b0 = blockIdx.x << 2;

    const _Float16* xl = lds;           // 16384 elems = 32 KB
    _Float16*       h0 = lds + 16384;   //  8192 elems = 16 KB
    _Float16*       h1 = lds;           //  4096 elems =  8 KB (over dead x)
    _Float16*       h2 = lds + 16384;   //  8192 elems = 16 KB (over dead h0)

    // ---- stage x columns: thread owns j; 4 coalesced scalar loads -> b64 row ----
#pragma unroll
    for (int c = 0; c < 4; ++c) {
        const int j = (c << 10) + t;
        const float v0 = x[(size_t)(b0 + 0) * 4096 + j];
        const float v1 = x[(size_t)(b0 + 1) * 4096 + j];
        const float v2 = x[(size_t)(b0 + 2) * 4096 + j];
        const float v3 = x[(size_t)(b0 + 3) * 4096 + j];
        h4 hv;
        hv[0] = (_Float16)v0; hv[1] = (_Float16)v1;
        hv[2] = (_Float16)v2; hv[3] = (_Float16)v3;
        *(h4*)(lds + (j << 2)) = hv;    // stride-1 ds_write_b64: conflict-free
    }
    __syncthreads();

    // ---- L0: 4096 -> 2048 ----
    layer_pass(xl, h0, idxS, probsH, t);
    layer_pass(xl, h0, idxS, probsH, t + 1024);
    __syncthreads();

    // ---- L1: 2048 -> 1024 ----
    layer_pass(h0, h1, idxS + 4096, probsH + 2048, t);
    __syncthreads();

    // ---- L2: 1024 -> 2048 ----
    layer_pass(h1, h2, idxS + 6144, probsH + 3072, t);
    layer_pass(h1, h2, idxS + 6144, probsH + 3072, t + 1024);
    __syncthreads();

    // ---- L3: 2048 -> 4096, direct global store (lanes sweep o: coalesced) ----
#pragma unroll
    for (int p = 0; p < 4; ++p) {
        const int o = (p << 10) + t;
        h4 r = gate4h(h2, idxS + 10240, probsH + 5120, o);
#pragma unroll
        for (int b = 0; b < 4; ++b)
            out[(size_t)(b0 + b) * 4096 + o] = (float)r[b];
    }
}

extern "C" void kernel_launch(void* const* d_in, const int* in_sizes, int n_in,
                              void* d_out, int out_size, void* d_ws, size_t ws_size,
                              hipStream_t stream) {
    const float* x        = (const float*)d_in[0];
    const float* w0       = (const float*)d_in[1];
    const float* w1       = (const float*)d_in[2];
    const float* w2       = (const float*)d_in[3];
    const float* w3       = (const float*)d_in[4];
    const int4*  idx0     = (const int4*)d_in[5];
    const int4*  idx1     = (const int4*)d_in[6];
    const int4*  idx2     = (const int4*)d_in[7];
    const int4*  idx3     = (const int4*)d_in[8];
    const int*   is_train = (const int*)d_in[9];
    float*       out      = (float*)d_out;

    // ws: probsH 9216*8B = 72 KB @0 | idxS 18432*16B = 288 KB @128K
    h4*   probsH = (h4*)d_ws;
    int4* idxS   = (int4*)((char*)d_ws + (128 << 10));

    prep_k<<<108, 256, 0, stream>>>(w0, w1, w2, w3, is_train,
                                    idx0, idx1, idx2, idx3, probsH, idxS);
    ddlg_fused<<<1024, 1024, 0, stream>>>(x, probsH, idxS, out);
}